// Round 1
// baseline (321.344 us; speedup 1.0000x reference)
//
#include <hip/hip_runtime.h>
#include <stdint.h>
#include <stddef.h>

#define DIM   256
#define NH    8
#define HD    32
#define BATCH 16
#define NTOK  4096   // 64*64

typedef __attribute__((ext_vector_type(8))) short short8;
typedef __attribute__((ext_vector_type(4))) float f32x4;

__device__ __forceinline__ unsigned short f2bf(float x){
  unsigned u = __float_as_uint(x);
  u += 0x7fffu + ((u >> 16) & 1u);       // RNE
  return (unsigned short)(u >> 16);
}
__device__ __forceinline__ float bf2f(unsigned short h){
  return __uint_as_float(((unsigned)h) << 16);
}

// ---------------- P1: x [b][c][n] f32 -> x_t [b][n][c] bf16 ----------------
__global__ __launch_bounds__(256) void k_transpose_x(const float* __restrict__ x,
                                                     unsigned short* __restrict__ xt){
  // grid (64 n-tiles, 4 c-tiles, 16 b)
  __shared__ float tile[64][65];
  const int b = blockIdx.z, c0 = blockIdx.y * 64, n0 = blockIdx.x * 64;
  const float* xb = x + (size_t)b * DIM * NTOK;
  const int t = threadIdx.x;
  #pragma unroll
  for (int p = 0; p < 4; p++){
    int idx = t + p * 256;
    int row = idx >> 4;          // c-local 0..63
    int col = (idx & 15) << 2;   // n-local 0..60
    float4 v = *(const float4*)(xb + (size_t)(c0 + row) * NTOK + n0 + col);
    tile[row][col] = v.x; tile[row][col+1] = v.y; tile[row][col+2] = v.z; tile[row][col+3] = v.w;
  }
  __syncthreads();
  unsigned short* xtb = xt + (size_t)b * NTOK * DIM;
  #pragma unroll
  for (int p = 0; p < 4; p++){
    int idx = t + p * 256;
    int nl = idx >> 4;           // n-local
    int cl = (idx & 15) << 2;    // c-local
    ushort4 o;
    o.x = f2bf(tile[cl+0][nl]); o.y = f2bf(tile[cl+1][nl]);
    o.z = f2bf(tile[cl+2][nl]); o.w = f2bf(tile[cl+3][nl]);
    *(ushort4*)(xtb + (size_t)(n0 + nl) * DIM + c0 + cl) = o;
  }
}

// ---------------- P2: convert Wqkv / Wproj to bf16 (same layout) ----------------
__global__ __launch_bounds__(256) void k_convert_w(const float* __restrict__ wqkv,
                                                   const float* __restrict__ wproj,
                                                   unsigned short* __restrict__ wq_bf,
                                                   unsigned short* __restrict__ wp_bf){
  int i = blockIdx.x * 256 + threadIdx.x;  // 65536 threads, 4 elems each
  if (i < 49152){
    float4 v = *(const float4*)(wqkv + (size_t)i * 4);
    ushort4 o = { f2bf(v.x), f2bf(v.y), f2bf(v.z), f2bf(v.w) };
    *(ushort4*)(wq_bf + (size_t)i * 4) = o;
  } else {
    int j = i - 49152;
    float4 v = *(const float4*)(wproj + (size_t)j * 4);
    ushort4 o = { f2bf(v.x), f2bf(v.y), f2bf(v.z), f2bf(v.w) };
    *(ushort4*)(wp_bf + (size_t)j * 4) = o;
  }
}

// ---------------- K1: qkv GEMM. D[n][o] = sum_c x_t[n][c] * Wqkv[o][c]; elu+1 on o<512 ----------------
// Block tile 128(n) x 128(o), Kc=64, 4 waves in 2x2, wave tile 64x64 = 4x4 MFMA 16x16x32.
// LDS staged in fragment-linear slabs: slab = tile*2+kk, within slab lane-linear 16B -> conflict-free b128.
__global__ __launch_bounds__(256) void k_qkv(const unsigned short* __restrict__ xt,
                                             const unsigned short* __restrict__ wbf,
                                             unsigned short* __restrict__ qkvt){
  __shared__ unsigned short As[8192];  // 16 slabs * 512 ushort
  __shared__ unsigned short Bs[8192];
  const int t = threadIdx.x;
  const int w = t >> 6, l = t & 63;
  const int t16 = l & 15, quad = l >> 4;
  const int wm = w >> 1, wn = w & 1;
  const int b = blockIdx.z;
  const int n0 = blockIdx.y * 128, o0 = blockIdx.x * 128;
  const unsigned short* A = xt + (size_t)b * NTOK * DIM;  // [n][256]
  const unsigned short* B = wbf;                          // [o][256]

  f32x4 acc[4][4];
  #pragma unroll
  for (int i = 0; i < 4; i++)
    #pragma unroll
    for (int j = 0; j < 4; j++){ acc[i][j][0]=0.f; acc[i][j][1]=0.f; acc[i][j][2]=0.f; acc[i][j][3]=0.f; }

  for (int k0 = 0; k0 < 256; k0 += 64){
    __syncthreads();
    #pragma unroll
    for (int j = 0; j < 4; j++){
      int slab = w * 4 + j;            // 0..15
      int tile = slab >> 1, kk = slab & 1;
      uint4 av = *(const uint4*)(A + (size_t)(n0 + tile*16 + t16) * DIM + k0 + kk*32 + quad*8);
      *(uint4*)(As + slab * 512 + l * 8) = av;
      uint4 bv = *(const uint4*)(B + (size_t)(o0 + tile*16 + t16) * DIM + k0 + kk*32 + quad*8);
      *(uint4*)(Bs + slab * 512 + l * 8) = bv;
    }
    __syncthreads();
    #pragma unroll
    for (int kk = 0; kk < 2; kk++){
      short8 a[4], bb[4];
      #pragma unroll
      for (int i = 0; i < 4; i++) a[i]  = *(const short8*)(As + ((wm*4 + i)*2 + kk) * 512 + l * 8);
      #pragma unroll
      for (int j = 0; j < 4; j++) bb[j] = *(const short8*)(Bs + ((wn*4 + j)*2 + kk) * 512 + l * 8);
      #pragma unroll
      for (int i = 0; i < 4; i++)
        #pragma unroll
        for (int j = 0; j < 4; j++)
          acc[i][j] = __builtin_amdgcn_mfma_f32_16x16x32_bf16(a[i], bb[j], acc[i][j], 0, 0, 0);
    }
  }

  unsigned short* out = qkvt + (size_t)b * NTOK * 768;
  #pragma unroll
  for (int i = 0; i < 4; i++){
    #pragma unroll
    for (int j = 0; j < 4; j++){
      int o = o0 + wn*64 + j*16 + t16;
      bool isqk = (o < 512);
      #pragma unroll
      for (int r = 0; r < 4; r++){
        int n = n0 + wm*64 + i*16 + quad*4 + r;
        float v = acc[i][j][r];
        if (isqk) v = (v > 0.f) ? (v + 1.f) : __expf(v);   // elu(v)+1
        out[(size_t)n * 768 + o] = f2bf(v);
      }
    }
  }
}

// ---------------- K2: kv partials. kvp[b][h][chunk][d][e] = sum_{n in chunk} knorm[n,d]*v[n,e] ----------------
__global__ __launch_bounds__(256) void k_kv(const unsigned short* __restrict__ qkvt,
                                            float* __restrict__ kvp){
  // grid (8 chunks, 8 h, 16 b)
  __shared__ unsigned short ks[64][32];
  __shared__ unsigned short vs[64][32];
  __shared__ float inv_s[64];
  const int t = threadIdx.x;
  const int chunk = blockIdx.x, h = blockIdx.y, b = blockIdx.z;
  const unsigned short* base = qkvt + (size_t)b * NTOK * 768;
  const int d = t >> 3, e0 = (t & 7) * 4;
  float a0=0.f, a1=0.f, a2=0.f, a3=0.f;
  const int n_base = chunk * 512;

  for (int c64 = 0; c64 < 8; c64++){
    __syncthreads();
    {
      int r = t >> 2, part = t & 3;
      int n = n_base + c64 * 64 + r;
      *(uint4*)(&ks[r][part*8]) = *(const uint4*)(base + (size_t)n*768 + 256 + h*32 + part*8);
      *(uint4*)(&vs[r][part*8]) = *(const uint4*)(base + (size_t)n*768 + 512 + h*32 + part*8);
    }
    __syncthreads();
    if (t < 64){
      float s = 0.f;
      #pragma unroll
      for (int dd = 0; dd < 32; dd += 2){
        unsigned u = *(const unsigned*)(&ks[t][dd]);
        s += bf2f((unsigned short)(u & 0xffff)) + bf2f((unsigned short)(u >> 16));
      }
      inv_s[t] = 1.0f / s;
    }
    __syncthreads();
    for (int r2 = 0; r2 < 64; r2++){
      float kf = bf2f(ks[r2][d]) * inv_s[r2];
      ushort4 vv = *(const ushort4*)(&vs[r2][e0]);
      a0 += kf * bf2f(vv.x); a1 += kf * bf2f(vv.y);
      a2 += kf * bf2f(vv.z); a3 += kf * bf2f(vv.w);
    }
  }
  float4 res = { a0, a1, a2, a3 };
  *(float4*)(kvp + (size_t)((b*8 + h)*8 + chunk) * 1024 + d*32 + e0) = res;
}

// ---------------- K2b: reduce 8 chunk partials -> kv[b][h][d][e] ----------------
__global__ __launch_bounds__(256) void k_kvred(const float* __restrict__ kvp,
                                               float* __restrict__ kv){
  int g = blockIdx.x * 256 + threadIdx.x;  // 32768
  int bh = g >> 8, rr = g & 255;
  int off = rr * 4;
  float4 a = { 0.f, 0.f, 0.f, 0.f };
  #pragma unroll
  for (int c = 0; c < 8; c++){
    float4 v = *(const float4*)(kvp + (size_t)(bh*8 + c) * 1024 + off);
    a.x += v.x; a.y += v.y; a.z += v.z; a.w += v.w;
  }
  *(float4*)(kv + (size_t)bh * 1024 + off) = a;
}

// ---------------- K3: attn[b][n][c] = (1/s_{n,h}) * sum_d qf[n,h,d] * kv[h][d][e], bf16 out ----------------
__global__ __launch_bounds__(256) void k_attn(const unsigned short* __restrict__ qkvt,
                                              const float* __restrict__ kv,
                                              unsigned short* __restrict__ attn){
  // grid (64 n-chunks, 16 b)
  __shared__ unsigned short qs[64][256];  // 32 KiB
  __shared__ float kvs[8192];             // 32 KiB [h][d][e]
  __shared__ float invs[64][8];
  const int t = threadIdx.x;
  const int b = blockIdx.y, n0 = blockIdx.x * 64;
  const unsigned short* base = qkvt + (size_t)b * NTOK * 768;

  #pragma unroll
  for (int p = 0; p < 8; p++){
    int idx = t + p * 256;             // 2048 x 16B
    int r = idx >> 5, c16 = idx & 31;
    *(uint4*)(&qs[r][c16*8]) = *(const uint4*)(base + (size_t)(n0 + r) * 768 + c16 * 8);
  }
  #pragma unroll
  for (int p = 0; p < 8; p++){
    int idx = t + p * 256;             // 2048 float4
    *(float4*)(kvs + (size_t)idx * 4) = *(const float4*)(kv + (size_t)b * 8192 + (size_t)idx * 4);
  }
  __syncthreads();
  #pragma unroll
  for (int p = 0; p < 2; p++){
    int idx = t + p * 256;             // 512 (n,h) sums
    int nl = idx >> 3, h = idx & 7;
    float s = 0.f;
    #pragma unroll
    for (int dd = 0; dd < 32; dd += 2){
      unsigned u = *(const unsigned*)(&qs[nl][h*32 + dd]);
      s += bf2f((unsigned short)(u & 0xffff)) + bf2f((unsigned short)(u >> 16));
    }
    invs[nl][h] = 1.0f / s;
  }
  __syncthreads();

  const int sub = t & 63, ng = t >> 6;
  const int c0 = sub * 4, h = sub >> 3, e0 = c0 & 31;
  unsigned short* ab = attn + (size_t)b * NTOK * 256;
  const float* kvh = kvs + h * 1024;
  for (int pass = 0; pass < 16; pass++){
    int nl = pass * 4 + ng;
    float a0=0.f, a1=0.f, a2=0.f, a3=0.f;
    #pragma unroll
    for (int dd = 0; dd < 32; dd += 2){
      unsigned u = *(const unsigned*)(&qs[nl][h*32 + dd]);
      float q0 = bf2f((unsigned short)(u & 0xffff));
      float q1 = bf2f((unsigned short)(u >> 16));
      float4 v0 = *(const float4*)(kvh + dd*32 + e0);
      float4 v1 = *(const float4*)(kvh + (dd+1)*32 + e0);
      a0 += q0*v0.x + q1*v1.x; a1 += q0*v0.y + q1*v1.y;
      a2 += q0*v0.z + q1*v1.z; a3 += q0*v0.w + q1*v1.w;
    }
    float inv = invs[nl][h];
    ushort4 o = { f2bf(a0*inv), f2bf(a1*inv), f2bf(a2*inv), f2bf(a3*inv) };
    *(ushort4*)(ab + (size_t)(n0 + nl) * 256 + c0) = o;
  }
}

// ---------------- K4: proj GEMM + bias + residual. out[b][o][n] = Wproj[o][c]·attn[n][c] + bproj[o] + x[b][o][n] ----------------
__global__ __launch_bounds__(256) void k_proj(const unsigned short* __restrict__ wp,
                                              const unsigned short* __restrict__ attn,
                                              const float* __restrict__ x,
                                              const float* __restrict__ bproj,
                                              float* __restrict__ out){
  // grid (2 o-tiles, 32 n-tiles, 16 b). Rows = o (A = Wproj), cols = n (B = attn).
  __shared__ unsigned short As[8192];
  __shared__ unsigned short Bs[8192];
  const int t = threadIdx.x;
  const int w = t >> 6, l = t & 63;
  const int t16 = l & 15, quad = l >> 4;
  const int wm = w >> 1, wn = w & 1;
  const int b = blockIdx.z;
  const int n0 = blockIdx.y * 128, o0 = blockIdx.x * 128;
  const unsigned short* A = wp;                              // [o][256]
  const unsigned short* B = attn + (size_t)b * NTOK * DIM;   // [n][256]

  f32x4 acc[4][4];
  #pragma unroll
  for (int i = 0; i < 4; i++)
    #pragma unroll
    for (int j = 0; j < 4; j++){ acc[i][j][0]=0.f; acc[i][j][1]=0.f; acc[i][j][2]=0.f; acc[i][j][3]=0.f; }

  for (int k0 = 0; k0 < 256; k0 += 64){
    __syncthreads();
    #pragma unroll
    for (int j = 0; j < 4; j++){
      int slab = w * 4 + j;
      int tile = slab >> 1, kk = slab & 1;
      uint4 av = *(const uint4*)(A + (size_t)(o0 + tile*16 + t16) * DIM + k0 + kk*32 + quad*8);
      *(uint4*)(As + slab * 512 + l * 8) = av;
      uint4 bv = *(const uint4*)(B + (size_t)(n0 + tile*16 + t16) * DIM + k0 + kk*32 + quad*8);
      *(uint4*)(Bs + slab * 512 + l * 8) = bv;
    }
    __syncthreads();
    #pragma unroll
    for (int kk = 0; kk < 2; kk++){
      short8 a[4], bb[4];
      #pragma unroll
      for (int i = 0; i < 4; i++) a[i]  = *(const short8*)(As + ((wm*4 + i)*2 + kk) * 512 + l * 8);
      #pragma unroll
      for (int j = 0; j < 4; j++) bb[j] = *(const short8*)(Bs + ((wn*4 + j)*2 + kk) * 512 + l * 8);
      #pragma unroll
      for (int i = 0; i < 4; i++)
        #pragma unroll
        for (int j = 0; j < 4; j++)
          acc[i][j] = __builtin_amdgcn_mfma_f32_16x16x32_bf16(a[i], bb[j], acc[i][j], 0, 0, 0);
    }
  }

  const float* xb = x + (size_t)b * DIM * NTOK;
  float* ob = out + (size_t)b * DIM * NTOK;
  #pragma unroll
  for (int i = 0; i < 4; i++){
    #pragma unroll
    for (int r = 0; r < 4; r++){
      int o = o0 + wm*64 + i*16 + quad*4 + r;
      float bias = bproj[o];
      #pragma unroll
      for (int j = 0; j < 4; j++){
        int n = n0 + wn*64 + j*16 + t16;
        float v = acc[i][j][r] + bias + xb[(size_t)o * NTOK + n];
        ob[(size_t)o * NTOK + n] = v;
      }
    }
  }
}

extern "C" void kernel_launch(void* const* d_in, const int* in_sizes, int n_in,
                              void* d_out, int out_size, void* d_ws, size_t ws_size,
                              hipStream_t stream){
  const float* x     = (const float*)d_in[0];
  const float* wqkv  = (const float*)d_in[1];
  const float* wproj = (const float*)d_in[2];
  const float* bproj = (const float*)d_in[3];
  float* out = (float*)d_out;
  char* ws = (char*)d_ws;

  // ws layout (needs ~133 MiB):
  unsigned short* xt    = (unsigned short*)(ws);                          // 32 MiB; dead after k_qkv
  unsigned short* qkvt  = (unsigned short*)(ws + ((size_t)32 << 20));     // 96 MiB
  unsigned short* wq_bf = (unsigned short*)(ws + ((size_t)128 << 20));    // 384 KiB
  unsigned short* wp_bf = (unsigned short*)(ws + ((size_t)128 << 20) + 393216);        // 128 KiB
  float* kvp = (float*)(ws + ((size_t)128 << 20) + 393216 + 131072);                   // 4 MiB
  float* kvm = (float*)(ws + ((size_t)128 << 20) + 393216 + 131072 + 4194304);         // 512 KiB
  unsigned short* attn = xt;  // alias: x_t no longer needed once attn is produced

  k_transpose_x<<<dim3(64, 4, 16), 256, 0, stream>>>(x, xt);
  k_convert_w  <<<dim3(256), 256, 0, stream>>>(wqkv, wproj, wq_bf, wp_bf);
  k_qkv        <<<dim3(6, 32, 16), 256, 0, stream>>>(xt, wq_bf, qkvt);
  k_kv         <<<dim3(8, 8, 16), 256, 0, stream>>>(qkvt, kvp);
  k_kvred      <<<dim3(128), 256, 0, stream>>>(kvp, kvm);
  k_attn       <<<dim3(64, 16), 256, 0, stream>>>(qkvt, kvm, attn);
  k_proj       <<<dim3(2, 32, 16), 256, 0, stream>>>(wp_bf, attn, x, bproj, out);
}

// Round 2
// 260.858 us; speedup vs baseline: 1.2319x; 1.2319x over previous
//
#include <hip/hip_runtime.h>
#include <stdint.h>
#include <stddef.h>

#define DIM   256
#define NH    8
#define HD    32
#define BATCH 16
#define NTOK  4096   // 64*64

typedef __attribute__((ext_vector_type(8))) short short8;
typedef __attribute__((ext_vector_type(4))) float f32x4;

__device__ __forceinline__ unsigned short f2bf(float x){
  unsigned u = __float_as_uint(x);
  u += 0x7fffu + ((u >> 16) & 1u);       // RNE
  return (unsigned short)(u >> 16);
}
__device__ __forceinline__ float bf2f(unsigned short h){
  return __uint_as_float(((unsigned)h) << 16);
}
__device__ __forceinline__ float elu1(float v){
  return (v > 0.f) ? (v + 1.f) : __expf(v);
}
// async global->LDS, 16B per lane. lds dest = wave-uniform base + lane*16.
__device__ __forceinline__ void gload_lds16(const void* g, void* lds){
  __builtin_amdgcn_global_load_lds(
      (const __attribute__((address_space(1))) unsigned int*)g,
      (__attribute__((address_space(3))) unsigned int*)lds, 16, 0, 0);
}

// ---------------- P1: x [b][c][n] f32 -> x_t [b][n][c] bf16 ----------------
__global__ __launch_bounds__(256) void k_transpose_x(const float* __restrict__ x,
                                                     unsigned short* __restrict__ xt){
  __shared__ float tile[64][65];
  const int b = blockIdx.z, c0 = blockIdx.y * 64, n0 = blockIdx.x * 64;
  const float* xb = x + (size_t)b * DIM * NTOK;
  const int t = threadIdx.x;
  #pragma unroll
  for (int p = 0; p < 4; p++){
    int idx = t + p * 256;
    int row = idx >> 4;
    int col = (idx & 15) << 2;
    float4 v = *(const float4*)(xb + (size_t)(c0 + row) * NTOK + n0 + col);
    tile[row][col] = v.x; tile[row][col+1] = v.y; tile[row][col+2] = v.z; tile[row][col+3] = v.w;
  }
  __syncthreads();
  unsigned short* xtb = xt + (size_t)b * NTOK * DIM;
  #pragma unroll
  for (int p = 0; p < 4; p++){
    int idx = t + p * 256;
    int nl = idx >> 4;
    int cl = (idx & 15) << 2;
    ushort4 o;
    o.x = f2bf(tile[cl+0][nl]); o.y = f2bf(tile[cl+1][nl]);
    o.z = f2bf(tile[cl+2][nl]); o.w = f2bf(tile[cl+3][nl]);
    *(ushort4*)(xtb + (size_t)(n0 + nl) * DIM + c0 + cl) = o;
  }
}

// ---------------- P2: convert Wqkv to bf16 ----------------
__global__ __launch_bounds__(256) void k_convert_w(const float* __restrict__ wqkv,
                                                   unsigned short* __restrict__ wq_bf){
  int i = blockIdx.x * 256 + threadIdx.x;  // 49152 threads, 4 elems each
  float4 v = *(const float4*)(wqkv + (size_t)i * 4);
  ushort4 o = { f2bf(v.x), f2bf(v.y), f2bf(v.z), f2bf(v.w) };
  *(ushort4*)(wq_bf + (size_t)i * 4) = o;
}

// ---------------- K1: qkv GEMM, A=Wqkv rows(o), B=xt cols(n). D[o][n].
// Epilogue: elu+1 (q,k), per-(n,head) normalize in-register, LDS-bounce stores:
//  q-blocks  -> qn  [b][n][c] bf16 (normalized)
//  k/v-blocks-> kvT [b][row][n] bf16 (k rows 0..255 normalized, v rows 256..511 raw)
__global__ __launch_bounds__(256) void k_qkv2(const unsigned short* __restrict__ wbf,
                                              const unsigned short* __restrict__ xt,
                                              unsigned short* __restrict__ qn,
                                              unsigned short* __restrict__ kvT){
  __shared__ __align__(16) unsigned short sh[17408];  // staging 16384, epi tile 128*136
  unsigned short* As = sh;          // 16 slabs * 512
  unsigned short* Bs = sh + 8192;
  const int t = threadIdx.x;
  const int w = t >> 6, l = t & 63;
  const int t16 = l & 15, quad = l >> 4;
  const int wm = w >> 1, wn = w & 1;
  const int bid = blockIdx.x;
  const int otile = bid >> 9;        // 0..5 ; same-(n,b) blocks differ by 512 -> same XCD
  const int nb = bid & 511;
  const int nt = nb >> 4, b = nb & 15;
  const int o0 = otile * 128, n0 = nt * 128;
  const unsigned short* A = wbf;                          // [768][256]
  const unsigned short* B = xt + (size_t)b * NTOK * DIM;  // [n][256]

  f32x4 acc[4][4];
  #pragma unroll
  for (int i = 0; i < 4; i++)
    #pragma unroll
    for (int j = 0; j < 4; j++){ acc[i][j][0]=0.f; acc[i][j][1]=0.f; acc[i][j][2]=0.f; acc[i][j][3]=0.f; }

  for (int k0 = 0; k0 < 256; k0 += 64){
    __syncthreads();
    #pragma unroll
    for (int j = 0; j < 4; j++){
      int s = w * 4 + j;             // 0..15
      int tile = s >> 1, kk = s & 1;
      gload_lds16(A + (size_t)(o0 + tile*16 + t16) * DIM + k0 + kk*32 + quad*8, As + s * 512);
      gload_lds16(B + (size_t)(n0 + tile*16 + t16) * DIM + k0 + kk*32 + quad*8, Bs + s * 512);
    }
    __syncthreads();
    #pragma unroll
    for (int kk = 0; kk < 2; kk++){
      short8 a[4], bb[4];
      #pragma unroll
      for (int i = 0; i < 4; i++) a[i]  = *(const short8*)(As + ((wm*4 + i)*2 + kk) * 512 + l * 8);
      #pragma unroll
      for (int j = 0; j < 4; j++) bb[j] = *(const short8*)(Bs + ((wn*4 + j)*2 + kk) * 512 + l * 8);
      #pragma unroll
      for (int i = 0; i < 4; i++)
        #pragma unroll
        for (int j = 0; j < 4; j++)
          acc[i][j] = __builtin_amdgcn_mfma_f32_16x16x32_bf16(a[i], bb[j], acc[i][j], 0, 0, 0);
    }
  }
  __syncthreads();   // all MFMA LDS reads done; sh reused for epilogue tile

  const bool isV = (o0 >= 512);
  const bool isQ = (o0 < 256);
  if (!isV){
    // feature map then per-(n,head) normalization. head_local = wm*2 + (i>>1)
    #pragma unroll
    for (int i = 0; i < 4; i++)
      #pragma unroll
      for (int j = 0; j < 4; j++)
        #pragma unroll
        for (int r = 0; r < 4; r++) acc[i][j][r] = elu1(acc[i][j][r]);
    float s[2][4];
    #pragma unroll
    for (int hi = 0; hi < 2; hi++)
      #pragma unroll
      for (int j = 0; j < 4; j++){
        float v = 0.f;
        #pragma unroll
        for (int ii = 0; ii < 2; ii++)
          #pragma unroll
          for (int r = 0; r < 4; r++) v += acc[hi*2 + ii][j][r];
        v += __shfl_xor(v, 16);
        v += __shfl_xor(v, 32);
        s[hi][j] = 1.0f / v;
      }
    #pragma unroll
    for (int i = 0; i < 4; i++)
      #pragma unroll
      for (int j = 0; j < 4; j++){
        float inv = s[i>>1][j];
        #pragma unroll
        for (int r = 0; r < 4; r++) acc[i][j][r] *= inv;
      }
  }

  // LDS bounce. q: tile[n_l][o_l]; k/v: tile[o_l][n_l]. stride 136 u16 (16B-aligned rows)
  if (isQ){
    #pragma unroll
    for (int i = 0; i < 4; i++)
      #pragma unroll
      for (int j = 0; j < 4; j++){
        int n_l = wn*64 + j*16 + t16;
        #pragma unroll
        for (int r = 0; r < 4; r++){
          int o_l = wm*64 + i*16 + quad*4 + r;
          sh[n_l*136 + o_l] = f2bf(acc[i][j][r]);
        }
      }
  } else {
    #pragma unroll
    for (int i = 0; i < 4; i++)
      #pragma unroll
      for (int j = 0; j < 4; j++){
        int n_l = wn*64 + j*16 + t16;
        #pragma unroll
        for (int r = 0; r < 4; r++){
          int o_l = wm*64 + i*16 + quad*4 + r;
          sh[o_l*136 + n_l] = f2bf(acc[i][j][r]);
        }
      }
  }
  __syncthreads();

  if (isQ){
    unsigned short* dst = qn + (size_t)b * NTOK * DIM;
    #pragma unroll
    for (int p = 0; p < 8; p++){
      int g = t + p * 256;
      int n_l = g >> 4, c = g & 15;
      uint4 v = *(const uint4*)(sh + n_l*136 + c*8);
      *(uint4*)(dst + (size_t)(n0 + n_l) * DIM + o0 + c*8) = v;
    }
  } else {
    unsigned short* dst = kvT + (size_t)b * 512 * NTOK + (size_t)(o0 - 256) * NTOK;
    #pragma unroll
    for (int p = 0; p < 8; p++){
      int g = t + p * 256;
      int o_l = g >> 4, c = g & 15;
      uint4 v = *(const uint4*)(sh + o_l*136 + c*8);
      *(uint4*)(dst + (size_t)o_l * NTOK + n0 + c*8) = v;
    }
  }
}

// ---------------- K2: kv partials via MFMA. kvT rows: k=[h*32+d], v=[256+h*32+e], n-contig.
// grid (4 nsplit, 8 h, 16 b), 4 waves/block, each wave K=256 chunk -> partial kv 32x32.
__global__ __launch_bounds__(256) void k_kv2(const unsigned short* __restrict__ kvT,
                                             float* __restrict__ kvp){
  const int t = threadIdx.x;
  const int w = t >> 6, l = t & 63;
  const int t16 = l & 15, quad = l >> 4;
  const int ns = blockIdx.x, h = blockIdx.y, b = blockIdx.z;
  const unsigned short* base = kvT + (size_t)b * 512 * NTOK;
  const int n_off = ns * 1024 + w * 256;

  f32x4 acc[2][2];
  #pragma unroll
  for (int i = 0; i < 2; i++)
    #pragma unroll
    for (int j = 0; j < 2; j++){ acc[i][j][0]=0.f; acc[i][j][1]=0.f; acc[i][j][2]=0.f; acc[i][j][3]=0.f; }

  const unsigned short* krow0 = base + (size_t)(h*32 + t16) * NTOK;
  const unsigned short* krow1 = krow0 + (size_t)16 * NTOK;
  const unsigned short* vrow0 = base + (size_t)(256 + h*32 + t16) * NTOK;
  const unsigned short* vrow1 = vrow0 + (size_t)16 * NTOK;

  for (int kk = 0; kk < 8; kk++){
    int n = n_off + kk*32 + quad*8;
    short8 a0 = *(const short8*)(krow0 + n);
    short8 a1 = *(const short8*)(krow1 + n);
    short8 b0 = *(const short8*)(vrow0 + n);
    short8 b1 = *(const short8*)(vrow1 + n);
    acc[0][0] = __builtin_amdgcn_mfma_f32_16x16x32_bf16(a0, b0, acc[0][0], 0, 0, 0);
    acc[0][1] = __builtin_amdgcn_mfma_f32_16x16x32_bf16(a0, b1, acc[0][1], 0, 0, 0);
    acc[1][0] = __builtin_amdgcn_mfma_f32_16x16x32_bf16(a1, b0, acc[1][0], 0, 0, 0);
    acc[1][1] = __builtin_amdgcn_mfma_f32_16x16x32_bf16(a1, b1, acc[1][1], 0, 0, 0);
  }
  float* dst = kvp + (size_t)(((b*8 + h)*16) + ns*4 + w) * 1024;
  #pragma unroll
  for (int ti = 0; ti < 2; ti++)
    #pragma unroll
    for (int tj = 0; tj < 2; tj++)
      #pragma unroll
      for (int r = 0; r < 4; r++)
        dst[(ti*16 + quad*4 + r)*32 + tj*16 + t16] = acc[ti][tj][r];
}

// ---------------- K3: reduce kv partials + fold Wproj: M[b][o][h*32+d] = sum_e Wp[o][h*32+e]*kv[d][e]
__global__ __launch_bounds__(256) void k_M(const float* __restrict__ kvp,
                                           const float* __restrict__ wproj,
                                           unsigned short* __restrict__ M){
  __shared__ float kvL[1024];
  __shared__ float wpL[8192];   // [o][e] 256x32
  const int t = threadIdx.x;
  const int h = blockIdx.x, b = blockIdx.y;
  const float* pbase = kvp + (size_t)((b*8 + h)*16) * 1024;
  {
    float4 a = {0.f,0.f,0.f,0.f};
    #pragma unroll
    for (int p = 0; p < 16; p++){
      float4 v = *(const float4*)(pbase + (size_t)p*1024 + t*4);
      a.x += v.x; a.y += v.y; a.z += v.z; a.w += v.w;
    }
    *(float4*)(kvL + t*4) = a;
  }
  #pragma unroll
  for (int p = 0; p < 8; p++){
    int idx = t + p * 256;          // float4 index over 256x32
    int o = idx >> 3, e4 = idx & 7;
    *(float4*)(wpL + o*32 + e4*4) = *(const float4*)(wproj + (size_t)o * DIM + h*32 + e4*4);
  }
  __syncthreads();
  float wr[32];
  #pragma unroll
  for (int e = 0; e < 32; e++) wr[e] = wpL[t*32 + e];
  unsigned short md[32];
  #pragma unroll
  for (int d = 0; d < 32; d++){
    float a = 0.f;
    #pragma unroll
    for (int e = 0; e < 32; e++) a += wr[e] * kvL[d*32 + e];
    md[d] = f2bf(a);
  }
  unsigned short* dst = M + (size_t)b * 65536 + (size_t)t * DIM + h*32;
  #pragma unroll
  for (int q = 0; q < 4; q++) *(uint4*)(dst + q*8) = *(const uint4*)(md + q*8);
}

// ---------------- K4: out GEMM. out[b][o][n] = sum_c M_b[o][c] * qn[b][n][c] + bproj[o] + x[b][o][n]
__global__ __launch_bounds__(256) void k_out(const unsigned short* __restrict__ M,
                                             const unsigned short* __restrict__ qn,
                                             const float* __restrict__ x,
                                             const float* __restrict__ bproj,
                                             float* __restrict__ out){
  __shared__ __align__(16) unsigned short As[8192];
  __shared__ __align__(16) unsigned short Bs[8192];
  const int t = threadIdx.x;
  const int w = t >> 6, l = t & 63;
  const int t16 = l & 15, quad = l >> 4;
  const int wm = w >> 1, wn = w & 1;
  const int b = blockIdx.z;
  const int n0 = blockIdx.y * 128, o0 = blockIdx.x * 128;
  const unsigned short* A = M + (size_t)b * 65536;        // [256][256]
  const unsigned short* B = qn + (size_t)b * NTOK * DIM;  // [n][256]

  f32x4 acc[4][4];
  #pragma unroll
  for (int i = 0; i < 4; i++)
    #pragma unroll
    for (int j = 0; j < 4; j++){ acc[i][j][0]=0.f; acc[i][j][1]=0.f; acc[i][j][2]=0.f; acc[i][j][3]=0.f; }

  for (int k0 = 0; k0 < 256; k0 += 64){
    __syncthreads();
    #pragma unroll
    for (int j = 0; j < 4; j++){
      int s = w * 4 + j;
      int tile = s >> 1, kk = s & 1;
      gload_lds16(A + (size_t)(o0 + tile*16 + t16) * DIM + k0 + kk*32 + quad*8, As + s * 512);
      gload_lds16(B + (size_t)(n0 + tile*16 + t16) * DIM + k0 + kk*32 + quad*8, Bs + s * 512);
    }
    __syncthreads();
    #pragma unroll
    for (int kk = 0; kk < 2; kk++){
      short8 a[4], bb[4];
      #pragma unroll
      for (int i = 0; i < 4; i++) a[i]  = *(const short8*)(As + ((wm*4 + i)*2 + kk) * 512 + l * 8);
      #pragma unroll
      for (int j = 0; j < 4; j++) bb[j] = *(const short8*)(Bs + ((wn*4 + j)*2 + kk) * 512 + l * 8);
      #pragma unroll
      for (int i = 0; i < 4; i++)
        #pragma unroll
        for (int j = 0; j < 4; j++)
          acc[i][j] = __builtin_amdgcn_mfma_f32_16x16x32_bf16(a[i], bb[j], acc[i][j], 0, 0, 0);
    }
  }

  const float* xb = x + (size_t)b * DIM * NTOK;
  float* ob = out + (size_t)b * DIM * NTOK;
  #pragma unroll
  for (int i = 0; i < 4; i++){
    #pragma unroll
    for (int r = 0; r < 4; r++){
      int o = o0 + wm*64 + i*16 + quad*4 + r;
      float bias = bproj[o];
      #pragma unroll
      for (int j = 0; j < 4; j++){
        int n = n0 + wn*64 + j*16 + t16;
        float v = acc[i][j][r] + bias + xb[(size_t)o * NTOK + n];
        ob[(size_t)o * NTOK + n] = v;
      }
    }
  }
}

extern "C" void kernel_launch(void* const* d_in, const int* in_sizes, int n_in,
                              void* d_out, int out_size, void* d_ws, size_t ws_size,
                              hipStream_t stream){
  const float* x     = (const float*)d_in[0];
  const float* wqkv  = (const float*)d_in[1];
  const float* wproj = (const float*)d_in[2];
  const float* bproj = (const float*)d_in[3];
  float* out = (float*)d_out;
  char* ws = (char*)d_ws;

  // ws layout (~128.4 MiB):
  unsigned short* xt   = (unsigned short*)(ws);                        // 32 MiB (dead after k_qkv2)
  unsigned short* qn   = (unsigned short*)(ws + ((size_t)32 << 20));   // 32 MiB [b][n][256]
  unsigned short* kvT  = (unsigned short*)(ws + ((size_t)64 << 20));   // 64 MiB [b][512][4096]
  unsigned short* wqbf = (unsigned short*)(ws + ((size_t)128 << 20));  // 384 KiB
  float* kvp = (float*)(ws);                                           // 8 MiB, reuses xt region
  unsigned short* M = (unsigned short*)(ws + ((size_t)8 << 20));       // 2 MiB, reuses xt region

  k_transpose_x<<<dim3(64, 4, 16), 256, 0, stream>>>(x, xt);
  k_convert_w  <<<dim3(192), 256, 0, stream>>>(wqkv, wqbf);
  k_qkv2       <<<dim3(3072), 256, 0, stream>>>(wqbf, xt, qn, kvT);
  k_kv2        <<<dim3(4, 8, 16), 256, 0, stream>>>(kvT, kvp);
  k_M          <<<dim3(8, 16), 256, 0, stream>>>(kvp, wproj, M);
  k_out        <<<dim3(2, 32, 16), 256, 0, stream>>>(M, qn, x, bproj, out);
}